// Round 3
// baseline (511.596 us; speedup 1.0000x reference)
//
#include <hip/hip_runtime.h>

#define LSTM_H 20

// sigmoid(x) = 1 / (1 + 2^(-x*log2(e)))
__device__ __forceinline__ float fsig(float x) {
    float e = __builtin_amdgcn_exp2f(x * -1.44269504088896340736f);
    return __builtin_amdgcn_rcpf(1.0f + e);
}
// tanh(x) = 2/(1 + 2^(-2x*log2(e))) - 1
__device__ __forceinline__ float ftanh(float x) {
    float e = __builtin_amdgcn_exp2f(x * -2.88539008177792681471f);
    return fmaf(__builtin_amdgcn_rcpf(1.0f + e), 2.0f, -1.0f);
}

__global__ __launch_bounds__(256) void coordwise_lstm_kernel(
    const float* __restrict__ params, const float* __restrict__ grads,
    const float* __restrict__ h0, const float* __restrict__ c0,
    const float* __restrict__ W_ih, const float* __restrict__ W_hh,
    const float* __restrict__ b_ih, const float* __restrict__ b_hh,
    const float* __restrict__ W_out, const float* __restrict__ b_out,
    float* __restrict__ out, int n)
{
    // UNIFORM control flow: clamp instead of early-return. A divergent return
    // here blocks SGPR formation of the (wave-uniform) weight loads -> each
    // becomes a per-lane global_load + 64-bit addr math (~1700 extra VALU ops,
    // the round-2 regression). Tail lanes recompute coord n-1 and write the
    // same value -> benign.
    int i = blockIdx.x * 256 + threadIdx.x;
    i = (i < n) ? i : (n - 1);

    const float g = grads[i];
    const float p = params[i];

    // h0/c0 rows: 20 floats = 80 B, 16B-aligned -> 5x float4 each.
    // Static indexing only -> arrays live in VGPRs.
    float hv[LSTM_H], cv[LSTM_H];
    const float4* h4 = reinterpret_cast<const float4*>(h0) + (size_t)i * (LSTM_H / 4);
    const float4* c4 = reinterpret_cast<const float4*>(c0) + (size_t)i * (LSTM_H / 4);
    #pragma unroll
    for (int q = 0; q < LSTM_H / 4; ++q) {
        float4 a = h4[q];
        hv[4*q+0] = a.x; hv[4*q+1] = a.y; hv[4*q+2] = a.z; hv[4*q+3] = a.w;
        float4 b = c4[q];
        cv[4*q+0] = b.x; cv[4*q+1] = b.y; cv[4*q+2] = b.z; cv[4*q+3] = b.w;
    }

    // Weight/bias reads: wave-uniform addresses, compile-time offsets, uniform
    // CF -> s_load_dwordx{8,16} + SGPR operands in v_fmac (0 VALU cost).
    // Bias form fmaf(..,b_ih)+fmaf(..,b_hh) keeps every op at <=1 SGPR read.
    float upd = b_out[0];
    #pragma unroll
    for (int k = 0; k < LSTM_H; ++k) {
        // PyTorch gate order: rows [0,20)=i, [20,40)=f, [40,60)=g, [60,80)=o
        float gi = fmaf(W_ih[2*k],              g, b_ih[k])
                 + fmaf(W_ih[2*k+1],            p, b_hh[k]);
        float gf = fmaf(W_ih[2*(k+LSTM_H)],     g, b_ih[k+LSTM_H])
                 + fmaf(W_ih[2*(k+LSTM_H)+1],   p, b_hh[k+LSTM_H]);
        float gg = fmaf(W_ih[2*(k+2*LSTM_H)],   g, b_ih[k+2*LSTM_H])
                 + fmaf(W_ih[2*(k+2*LSTM_H)+1], p, b_hh[k+2*LSTM_H]);
        float go = fmaf(W_ih[2*(k+3*LSTM_H)],   g, b_ih[k+3*LSTM_H])
                 + fmaf(W_ih[2*(k+3*LSTM_H)+1], p, b_hh[k+3*LSTM_H]);
        #pragma unroll
        for (int kk = 0; kk < LSTM_H; ++kk) {
            const float h = hv[kk];
            gi = fmaf(W_hh[(k)*LSTM_H            + kk], h, gi);
            gf = fmaf(W_hh[(k+LSTM_H)*LSTM_H     + kk], h, gf);
            gg = fmaf(W_hh[(k+2*LSTM_H)*LSTM_H   + kk], h, gg);
            go = fmaf(W_hh[(k+3*LSTM_H)*LSTM_H   + kk], h, go);
        }
        const float c1 = fmaf(fsig(gf), cv[k], fsig(gi) * ftanh(gg));
        const float h1 = fsig(go) * ftanh(c1);
        upd = fmaf(W_out[k], h1, upd);
    }
    out[i] = upd;
}

extern "C" void kernel_launch(void* const* d_in, const int* in_sizes, int n_in,
                              void* d_out, int out_size, void* d_ws, size_t ws_size,
                              hipStream_t stream) {
    const float* params = (const float*)d_in[0];
    const float* grads  = (const float*)d_in[1];
    const float* h0     = (const float*)d_in[2];
    const float* c0     = (const float*)d_in[3];
    const float* W_ih   = (const float*)d_in[4];
    const float* W_hh   = (const float*)d_in[5];
    const float* b_ih   = (const float*)d_in[6];
    const float* b_hh   = (const float*)d_in[7];
    const float* W_out  = (const float*)d_in[8];
    const float* b_out  = (const float*)d_in[9];
    float* out = (float*)d_out;

    const int n = in_sizes[0];
    const int blocks = (n + 255) / 256;
    hipLaunchKernelGGL(coordwise_lstm_kernel, dim3(blocks), dim3(256), 0, stream,
                       params, grads, h0, c0, W_ih, W_hh, b_ih, b_hh, W_out, b_out,
                       out, n);
}

// Round 5
// 367.457 us; speedup vs baseline: 1.3923x; 1.3923x over previous
//
#include <hip/hip_runtime.h>

#define LSTM_H 20
#define LSTM_4H 80

// sigmoid(x) = 1 / (1 + 2^(-x*log2(e)))
__device__ __forceinline__ float fsig(float x) {
    float e = __builtin_amdgcn_exp2f(x * -1.44269504088896340736f);
    return __builtin_amdgcn_rcpf(1.0f + e);
}
// tanh(x) = 2/(1 + 2^(-2x*log2(e))) - 1
__device__ __forceinline__ float ftanh(float x) {
    float e = __builtin_amdgcn_exp2f(x * -2.88539008177792681471f);
    return fmaf(__builtin_amdgcn_rcpf(1.0f + e), 2.0f, -1.0f);
}

__global__ __launch_bounds__(256) void coordwise_lstm_kernel(
    const float* __restrict__ params, const float* __restrict__ grads,
    const float* __restrict__ h0, const float* __restrict__ c0,
    const float* __restrict__ W_ih, const float* __restrict__ W_hh,
    const float* __restrict__ b_ih, const float* __restrict__ b_hh,
    const float* __restrict__ W_out, const float* __restrict__ b_out,
    float* __restrict__ out, int n)
{
    // Weights in LDS, read broadcast (all lanes same addr -> conflict-free).
    // FULL static unrolling everywhere: LDS reads become base + offset:imm
    // (zero VALU addr math), private arrays live in VGPRs (zero scratch).
    __shared__ float  sWhh[LSTM_4H * LSTM_H];   // [80][20], rows 16B-aligned
    __shared__ float2 sWih[LSTM_4H];            // (w_grad, w_param) per row
    __shared__ float  sB[LSTM_4H];              // b_ih + b_hh
    __shared__ float  sWout[LSTM_H];
    __shared__ float  sBout;

    for (int t = threadIdx.x; t < LSTM_4H * LSTM_H; t += 256) sWhh[t] = W_hh[t];
    for (int t = threadIdx.x; t < LSTM_4H;          t += 256) {
        sWih[t] = make_float2(W_ih[2*t], W_ih[2*t+1]);
        sB[t]   = b_ih[t] + b_hh[t];
    }
    if (threadIdx.x < LSTM_H) sWout[threadIdx.x] = W_out[threadIdx.x];
    if (threadIdx.x == 0) sBout = b_out[0];
    __syncthreads();

    // Uniform control flow: clamp, not early-return. Tail lanes redo coord
    // n-1 and write the same value (benign).
    int i = blockIdx.x * 256 + threadIdx.x;
    i = (i < n) ? i : (n - 1);

    const float g = grads[i];
    const float p = params[i];

    float hv[LSTM_H], cv[LSTM_H];
    const float4* h4 = reinterpret_cast<const float4*>(h0) + (size_t)i * (LSTM_H / 4);
    const float4* c4 = reinterpret_cast<const float4*>(c0) + (size_t)i * (LSTM_H / 4);
    #pragma unroll
    for (int q = 0; q < LSTM_H / 4; ++q) {
        float4 a = h4[q];
        hv[4*q+0] = a.x; hv[4*q+1] = a.y; hv[4*q+2] = a.z; hv[4*q+3] = a.w;
        float4 b = c4[q];
        cv[4*q+0] = b.x; cv[4*q+1] = b.y; cv[4*q+2] = b.z; cv[4*q+3] = b.w;
    }

    float upd = sBout;
    #pragma unroll
    for (int k = 0; k < LSTM_H; ++k) {
        // PyTorch gate order: rows [0,20)=i, [20,40)=f, [40,60)=g, [60,80)=o
        float2 wxi = sWih[k];
        float2 wxf = sWih[k +   LSTM_H];
        float2 wxg = sWih[k + 2*LSTM_H];
        float2 wxo = sWih[k + 3*LSTM_H];
        float gi = fmaf(wxi.x, g, fmaf(wxi.y, p, sB[k]));
        float gf = fmaf(wxf.x, g, fmaf(wxf.y, p, sB[k +   LSTM_H]));
        float gg = fmaf(wxg.x, g, fmaf(wxg.y, p, sB[k + 2*LSTM_H]));
        float go = fmaf(wxo.x, g, fmaf(wxo.y, p, sB[k + 3*LSTM_H]));

        const float4* wi4 = reinterpret_cast<const float4*>(&sWhh[(k)           * LSTM_H]);
        const float4* wf4 = reinterpret_cast<const float4*>(&sWhh[(k +   LSTM_H) * LSTM_H]);
        const float4* wg4 = reinterpret_cast<const float4*>(&sWhh[(k + 2*LSTM_H) * LSTM_H]);
        const float4* wo4 = reinterpret_cast<const float4*>(&sWhh[(k + 3*LSTM_H) * LSTM_H]);
        #pragma unroll
        for (int q = 0; q < LSTM_H / 4; ++q) {
            float4 wi = wi4[q], wf = wf4[q], wg = wg4[q], wo = wo4[q];
            gi = fmaf(wi.x, hv[4*q+0], gi); gi = fmaf(wi.y, hv[4*q+1], gi);
            gi = fmaf(wi.z, hv[4*q+2], gi); gi = fmaf(wi.w, hv[4*q+3], gi);
            gf = fmaf(wf.x, hv[4*q+0], gf); gf = fmaf(wf.y, hv[4*q+1], gf);
            gf = fmaf(wf.z, hv[4*q+2], gf); gf = fmaf(wf.w, hv[4*q+3], gf);
            gg = fmaf(wg.x, hv[4*q+0], gg); gg = fmaf(wg.y, hv[4*q+1], gg);
            gg = fmaf(wg.z, hv[4*q+2], gg); gg = fmaf(wg.w, hv[4*q+3], gg);
            go = fmaf(wo.x, hv[4*q+0], go); go = fmaf(wo.y, hv[4*q+1], go);
            go = fmaf(wo.z, hv[4*q+2], go); go = fmaf(wo.w, hv[4*q+3], go);
        }
        const float c1 = fmaf(fsig(gf), cv[k], fsig(gi) * ftanh(gg));
        const float h1 = fsig(go) * ftanh(c1);
        upd = fmaf(sWout[k], h1, upd);
    }
    out[i] = upd;
}

extern "C" void kernel_launch(void* const* d_in, const int* in_sizes, int n_in,
                              void* d_out, int out_size, void* d_ws, size_t ws_size,
                              hipStream_t stream) {
    const float* params = (const float*)d_in[0];
    const float* grads  = (const float*)d_in[1];
    const float* h0     = (const float*)d_in[2];
    const float* c0     = (const float*)d_in[3];
    const float* W_ih   = (const float*)d_in[4];
    const float* W_hh   = (const float*)d_in[5];
    const float* b_ih   = (const float*)d_in[6];
    const float* b_hh   = (const float*)d_in[7];
    const float* W_out  = (const float*)d_in[8];
    const float* b_out  = (const float*)d_in[9];
    float* out = (float*)d_out;

    const int n = in_sizes[0];
    const int blocks = (n + 255) / 256;
    hipLaunchKernelGGL(coordwise_lstm_kernel, dim3(blocks), dim3(256), 0, stream,
                       params, grads, h0, c0, W_ih, W_hh, b_ih, b_hh, W_out, b_out,
                       out, n);
}